// Round 1
// baseline (225.762 us; speedup 1.0000x reference)
//
#include <hip/hip_runtime.h>
#include <math.h>

#define H 2048
#define V 50257
#define S 2048

__device__ inline float dot4(float4 a, float4 b) {
  return a.x * b.x + a.y * b.y + a.z * b.z + a.w * b.w;
}

__device__ inline float wave_sum(float v) {
#pragma unroll
  for (int o = 32; o > 0; o >>= 1) v += __shfl_down(v, o, 64);
  return v;
}

__device__ inline float wave_max(float v) {
#pragma unroll
  for (int o = 32; o > 0; o >>= 1) v = fmaxf(v, __shfl_down(v, o, 64));
  return v;
}

// One block (256 threads) per output unit i: 6 dot products of length H.
__global__ __launch_bounds__(256) void gru_kernel(
    const float* __restrict__ w_ih, const float* __restrict__ w_hh,
    const float* __restrict__ b_ih, const float* __restrict__ b_hh,
    const float* __restrict__ x_base, const int* __restrict__ word,
    const float* __restrict__ hprev,
    float* __restrict__ hout_ws, float* __restrict__ hout_d) {
  const float* x = word ? (x_base + (size_t)word[0] * H) : x_base;
  const int i = blockIdx.x;
  const int t = threadIdx.x;
  const float4* x4 = (const float4*)x;
  const float4* h4 = (const float4*)hprev;
  float acc[6];
#pragma unroll
  for (int d = 0; d < 6; d++) acc[d] = 0.f;
#pragma unroll
  for (int g = 0; g < 3; g++) {
    const float4* wi = (const float4*)(w_ih + (size_t)(g * H + i) * H);
    const float4* wh = (const float4*)(w_hh + (size_t)(g * H + i) * H);
    float4 xa = x4[t], xb = x4[t + 256];
    float4 ha = h4[t], hb = h4[t + 256];
    acc[g]     = dot4(wi[t], xa) + dot4(wi[t + 256], xb);
    acc[3 + g] = dot4(wh[t], ha) + dot4(wh[t + 256], hb);
  }
  __shared__ float red[6][4];
  const int lane = t & 63, wid = t >> 6;
#pragma unroll
  for (int d = 0; d < 6; d++) {
    float s = wave_sum(acc[d]);
    if (lane == 0) red[d][wid] = s;
  }
  __syncthreads();
  if (t == 0) {
    float gi_r = red[0][0] + red[0][1] + red[0][2] + red[0][3] + b_ih[i];
    float gi_z = red[1][0] + red[1][1] + red[1][2] + red[1][3] + b_ih[H + i];
    float gi_n = red[2][0] + red[2][1] + red[2][2] + red[2][3] + b_ih[2 * H + i];
    float gh_r = red[3][0] + red[3][1] + red[3][2] + red[3][3] + b_hh[i];
    float gh_z = red[4][0] + red[4][1] + red[4][2] + red[4][3] + b_hh[H + i];
    float gh_n = red[5][0] + red[5][1] + red[5][2] + red[5][3] + b_hh[2 * H + i];
    float r = 1.f / (1.f + expf(-(gi_r + gh_r)));
    float z = 1.f / (1.f + expf(-(gi_z + gh_z)));
    float n = tanhf(gi_n + r * gh_n);
    float h = (1.f - z) * n + z * hprev[i];
    hout_ws[i] = h;
    hout_d[i] = h;
  }
}

// part[jt][k] = sum_{j in tile jt} coef[j] * mat[j][k].  grid=(8, 32), 64 rows/tile.
__global__ __launch_bounds__(256) void colsum_part_kernel(
    const float* __restrict__ mat, const float* __restrict__ coef,
    float* __restrict__ part) {
  const int k = blockIdx.x * 256 + threadIdx.x;
  const int jt = blockIdx.y;
  const int j0 = jt * 64;
  float acc = 0.f;
#pragma unroll 4
  for (int j = j0; j < j0 + 64; j++)
    acc += coef[j] * mat[(size_t)j * H + k];
  part[(size_t)jt * H + k] = acc;
}

// out[k] = sum over 32 partial tiles.  grid = 8 blocks x 256.
__global__ __launch_bounds__(256) void combine_kernel(
    const float* __restrict__ part, float* __restrict__ out) {
  const int k = blockIdx.x * 256 + threadIdx.x;
  float acc = 0.f;
#pragma unroll
  for (int jt = 0; jt < 32; jt++) acc += part[(size_t)jt * H + k];
  out[k] = acc;
}

// e[row] = dot(enc[row], v).  One wave per row, 4 rows per block.
__global__ __launch_bounds__(256) void energies_kernel(
    const float* __restrict__ enc, const float* __restrict__ v,
    float* __restrict__ e) {
  const int wid = threadIdx.x >> 6, lane = threadIdx.x & 63;
  const int row = blockIdx.x * 4 + wid;
  const float4* r4 = (const float4*)(enc + (size_t)row * H);
  const float4* v4 = (const float4*)v;
  float acc = 0.f;
#pragma unroll
  for (int k = 0; k < 8; k++) {
    int idx = lane + 64 * k;
    acc += dot4(r4[idx], v4[idx]);
  }
  acc = wave_sum(acc);
  if (lane == 0) e[row] = acc;
}

// softmax over 2048 energies; writes weights to ws and to d_out attn slot.
__global__ __launch_bounds__(1024) void softmax_kernel(
    const float* __restrict__ e, float* __restrict__ w,
    float* __restrict__ w2) {
  const int t = threadIdx.x;
  const int lane = t & 63, wid = t >> 6;
  __shared__ float sm[16];
  __shared__ float ss[16];
  float e0 = e[t], e1 = e[t + 1024];
  float m = fmaxf(e0, e1);
  float mw = wave_max(m);
  if (lane == 0) sm[wid] = mw;
  __syncthreads();
  if (t == 0) {
    float mm = sm[0];
    for (int i = 1; i < 16; i++) mm = fmaxf(mm, sm[i]);
    sm[0] = mm;
  }
  __syncthreads();
  const float M = sm[0];
  float p0 = expf(e0 - M), p1 = expf(e1 - M);
  float sw = wave_sum(p0 + p1);
  if (lane == 0) ss[wid] = sw;
  __syncthreads();
  if (t == 0) {
    float tt = 0.f;
    for (int i = 0; i < 16; i++) tt += ss[i];
    ss[0] = tt;
  }
  __syncthreads();
  const float inv = 1.f / ss[0];
  w[t] = p0 * inv;
  w[t + 1024] = p1 * inv;
  w2[t] = p0 * inv;
  w2[t + 1024] = p1 * inv;
}

// logits[row] = dot(w_out[row, 0:4096], u) + b_out[row]. One wave/row.
__global__ __launch_bounds__(256) void logits_kernel(
    const float* __restrict__ w_out, const float* __restrict__ b_out,
    const float* __restrict__ u, float* __restrict__ logits) {
  const int wid = threadIdx.x >> 6, lane = threadIdx.x & 63;
  const int row = blockIdx.x * 4 + wid;
  if (row >= V) return;
  const float4* r4 = (const float4*)(w_out + (size_t)row * (2 * H));
  const float4* u4 = (const float4*)u;
  float acc = 0.f;
#pragma unroll
  for (int k = 0; k < 16; k++) {
    int idx = lane + 64 * k;
    acc += dot4(r4[idx], u4[idx]);
  }
  acc = wave_sum(acc);
  if (lane == 0) logits[row] = acc + b_out[row];
}

// max + log-sum-exp over V logits (single block, 1024 threads).
__global__ __launch_bounds__(1024) void lse_kernel(
    const float* __restrict__ l, float* __restrict__ mlse) {
  const int t = threadIdx.x;
  const int lane = t & 63, wid = t >> 6;
  __shared__ float sm[16];
  __shared__ float ss[16];
  float m = -INFINITY;
  for (int i = t; i < V; i += 1024) m = fmaxf(m, l[i]);
  float mw = wave_max(m);
  if (lane == 0) sm[wid] = mw;
  __syncthreads();
  if (t == 0) {
    float mm = sm[0];
    for (int i = 1; i < 16; i++) mm = fmaxf(mm, sm[i]);
    sm[0] = mm;
  }
  __syncthreads();
  const float M = sm[0];
  float s = 0.f;
  for (int i = t; i < V; i += 1024) s += expf(l[i] - M);
  float sw = wave_sum(s);
  if (lane == 0) ss[wid] = sw;
  __syncthreads();
  if (t == 0) {
    float tt = 0.f;
    for (int i = 0; i < 16; i++) tt += ss[i];
    mlse[0] = M;
    mlse[1] = logf(tt);
  }
}

__global__ __launch_bounds__(256) void final_kernel(
    float* __restrict__ out, const float* __restrict__ mlse) {
  const int i = blockIdx.x * 256 + threadIdx.x;
  if (i < V) out[i] -= (mlse[0] + mlse[1]);
}

extern "C" void kernel_launch(void* const* d_in, const int* in_sizes, int n_in,
                              void* d_out, int out_size, void* d_ws, size_t ws_size,
                              hipStream_t stream) {
  const int*   word  = (const int*)d_in[0];
  const float* lasth = (const float*)d_in[1];   // (2,1,H)
  const float* enc   = (const float*)d_in[2];   // (S,1,H) -> contiguous S x H
  const float* emb   = (const float*)d_in[3];   // (V,H)
  const float* w_ih0 = (const float*)d_in[4];
  const float* w_hh0 = (const float*)d_in[5];
  const float* b_ih0 = (const float*)d_in[6];
  const float* b_hh0 = (const float*)d_in[7];
  const float* w_ih1 = (const float*)d_in[8];
  const float* w_hh1 = (const float*)d_in[9];
  const float* b_ih1 = (const float*)d_in[10];
  const float* b_hh1 = (const float*)d_in[11];
  const float* wa    = (const float*)d_in[12];
  // d_in[13] = ba: adds a constant to all energies -> cancels in softmax.
  const float* w_out = (const float*)d_in[14];
  const float* b_out = (const float*)d_in[15];

  float* out      = (float*)d_out;            // [0:V)        log_softmax
  float* h0_out   = out + V;                  // [V : V+H)    hidden[0]
  float* h1_out   = out + V + H;              // [V+H : V+2H) hidden[1]
  float* attn_out = out + V + 2 * H;          // [V+2H : V+2H+S)

  float* wsf  = (float*)d_ws;
  float* part = wsf;                // 32 * H = 65536
  float* v    = wsf + 65536;        // H
  float* e    = wsf + 67584;        // S
  float* w    = wsf + 69632;        // S
  float* u    = wsf + 71680;        // 2H: [h1 | context]
  float* h0   = wsf + 75776;        // H
  float* mlse = wsf + 77824;        // 2

  // GRU layer 0 (x = emb[word]) and layer 1 (x = h0)
  gru_kernel<<<H, 256, 0, stream>>>(w_ih0, w_hh0, b_ih0, b_hh0, emb, word,
                                    lasth, h0, h0_out);
  gru_kernel<<<H, 256, 0, stream>>>(w_ih1, w_hh1, b_ih1, b_hh1, h0, nullptr,
                                    lasth + H, u, h1_out);
  // v = wa^T @ h1   (u[0:H] holds h1)
  colsum_part_kernel<<<dim3(8, 32), 256, 0, stream>>>(wa, u, part);
  combine_kernel<<<8, 256, 0, stream>>>(part, v);
  // energies[s] = dot(v, enc[s])
  energies_kernel<<<S / 4, 256, 0, stream>>>(enc, v, e);
  // attn weights
  softmax_kernel<<<1, 1024, 0, stream>>>(e, w, attn_out);
  // context = enc^T @ w  -> u[H:2H]
  colsum_part_kernel<<<dim3(8, 32), 256, 0, stream>>>(enc, w, part);
  combine_kernel<<<8, 256, 0, stream>>>(part, u + H);
  // logits into d_out[0:V], then log-softmax in place
  logits_kernel<<<(V + 3) / 4, 256, 0, stream>>>(w_out, b_out, u, out);
  lse_kernel<<<1, 1024, 0, stream>>>(out, mlse);
  final_kernel<<<(V + 255) / 256, 256, 0, stream>>>(out, mlse);
}